// Round 6
// baseline (54.643 us; speedup 1.0000x reference)
//
#include <hip/hip_runtime.h>
#include <stdint.h>

#define UNITS  512
#define IN_DIM 1024
#define KCONN  32
#define BATCH  16384
#define BT     16      // batches per block tile (f32 row = 64B)

// ---------------- Kernel 1: top-32 per unit (DPP, no DS ops) ----------------
// pert[u,i] = D[u,i] + GN[0,u,i]; select the 32 largest. Only the index SET
// matters downstream (one-hots are summed), so selection order / exact
// tie-break is irrelevant (values are continuous; exact ties ~never happen).
// Output unit-major: pkU[u*32 + k] = { px, bits(W[u,i]) } where
//   px = i*64 + ((i&3)<<4)  -- pre-swizzled LDS row address (row i, chunk i&3
//   holds batches 0..3; gather lane cq reads chunk (i&3)^cq at px ^ (cq<<4)).

template <int CTRL, int RM>
__device__ __forceinline__ float dppmax(float m) {
    // lanes with no valid dpp source keep old value, harmless for max
    int t = __builtin_amdgcn_update_dpp(0xFF800000, __float_as_int(m),
                                        CTRL, RM, 0xf, false);
    return fmaxf(m, __int_as_float(t));
}

__global__ __launch_bounds__(64) void topk_kernel(const float* __restrict__ D,
                                                  const float* __restrict__ GN,
                                                  const float* __restrict__ W,
                                                  uint2* __restrict__ pkU) {
    const int u = blockIdx.x;
    const int l = threadIdx.x;

    float cand[16];
#pragma unroll
    for (int j = 0; j < 16; ++j) {
        int i = l + 64 * j;                          // coalesced
        cand[j] = D[u * IN_DIM + i] + GN[u * IN_DIM + i];
    }

    int mykeep = -1;

    for (int t = 0; t < KCONN; ++t) {
        // local argmax over 16 register slots
        float bv = cand[0];
        int bs = 0;
#pragma unroll
        for (int j = 1; j < 16; ++j) {
            bool gt = cand[j] > bv;
            bv = gt ? cand[j] : bv;
            bs = gt ? j : bs;
        }
        // wave max via DPP (VALU pipe only): row_shr 1,2,4,8 + row_bcast15/31
        float m = bv;
        m = dppmax<0x111, 0xf>(m);
        m = dppmax<0x112, 0xf>(m);
        m = dppmax<0x114, 0xf>(m);
        m = dppmax<0x118, 0xf>(m);
        m = dppmax<0x142, 0xa>(m);   // row_bcast15 -> rows 1,3
        m = dppmax<0x143, 0xc>(m);   // row_bcast31 -> rows 2,3
        float gmax = __int_as_float(__builtin_amdgcn_readlane(__float_as_int(m), 63));

        unsigned long long mask = __ballot(bv == gmax);
        int owner = __ffsll((long long)mask) - 1;
        int slot = __builtin_amdgcn_readlane(bs, owner);
        int idx = slot * 64 + owner;                 // global column index

        if (l == t) mykeep = idx;
        // removal (uniform, unrolled -> no scratch)
        bool own = (l == owner);
#pragma unroll
        for (int j = 0; j < 16; ++j)
            cand[j] = (own && j == slot) ? -__builtin_huge_valf() : cand[j];
    }

    if (l < KCONN) {
        int i = mykeep;
        float w = W[u * IN_DIM + i];
        uint32_t px = ((uint32_t)i << 6) | (((uint32_t)i & 3u) << 4);
        pkU[u * KCONN + l] = make_uint2(px, __float_as_uint(w));
    }
}

// ---------------- Kernel 2: sparse gather-GEMM ----------------
// y[b,u] = bias[u] + sum_k W[u,i] * x[b,i]
// LDS: xs_T[i][b] f32, 16 batches/row = 64B rows, 64 KB -> 2 blocks/CU.
// Chunk swizzle (16B granule): chunk for batches 4c..4c+3 of row i lives at
//   i*64 + 16*(c ^ (i&3)).
// Gather: QUAD-UNIFORM rows -- the 4 lanes of a quad read the SAME row
// (same unit,k), one 16B chunk each => every row-read covers 16 banks exactly
// once; only the 2 possible row positions (i even/odd *64 mod 128) vary =>
// ~1.2x residual imbalance instead of r5's 2x random-chunk conflicts.
// Each quad owns 4 units (u = w*64 + q*4 + j); pk is unit-major (256B/unit,
// L1-friendly, quad-broadcast). acc[4][4] static; y stored as float4 over j
// (4x256B contiguous segments per store instr).

// 4x4 transpose within a quad (r2-r5 verified): input lane r holds row r's
// 4 cols {c..c+3}; output lane r holds col c+r's 4 rows.
#define QTRANS(f0, f1, f2, f3, o0, o1, o2, o3)                                   \
    {                                                                            \
        float t0 = r1 ? f1 : f0, t1 = r1 ? f2 : f1, t2 = r1 ? f3 : f2,           \
              t3 = r1 ? f0 : f3;                                                 \
        float g0 = r2m ? t2 : t0, g1 = r2m ? t3 : t1, g2 = r2m ? t0 : t2,        \
              g3 = r2m ? t1 : t3;                                                \
        float m0 = __shfl(g0, qb | (r & 3), 64);                                 \
        float m1 = __shfl(g1, qb | ((r - 1) & 3), 64);                           \
        float m2 = __shfl(g2, qb | ((r - 2) & 3), 64);                           \
        float m3 = __shfl(g3, qb | ((r - 3) & 3), 64);                           \
        float e0 = m0, e1 = m3, e2 = m2, e3 = m1;                                \
        float s0 = r1 ? e3 : e0, s1 = r1 ? e0 : e1, s2 = r1 ? e1 : e2,           \
              s3 = r1 ? e2 : e3;                                                 \
        o0 = r2m ? s2 : s0; o1 = r2m ? s3 : s1; o2 = r2m ? s0 : s2;              \
        o3 = r2m ? s1 : s3;                                                      \
    }

__global__ __launch_bounds__(512, 4) void spmm_kernel(const float* __restrict__ x,
                                                      const float* __restrict__ bias,
                                                      const uint2* __restrict__ pkU,
                                                      float* __restrict__ y) {
    __shared__ char xsb[65536];                     // 64 KB -> 2 blocks/CU

    const int tid = threadIdx.x;
    const int w = tid >> 6;                         // wave 0..7
    const int l = tid & 63;
    const int r = l & 3;                            // quad lane
    const int q16 = l >> 2;                         // quad id 0..15
    const int b0 = blockIdx.x * BT;

    // ---- stage: x[b0..b0+15][:] f32 -> xs_T[i][b], transposed, swizzled ----
    // wave w: batch quad bq = w&3 (batches 4bq..4bq+3), col half ch = w>>2.
    const int bq = w & 3, ch = w >> 2;
    const float* xrow = x + (size_t)(b0 + 4 * bq + r) * IN_DIM;
    const int r1 = r & 1, r2m = r & 2;
    const int qb = l & ~3;
#pragma unroll
    for (int j = 0; j < 8; ++j) {
        const int c = ch * 512 + q16 * 4 + j * 64;
        float4 v = *(const float4*)(xrow + c);
        float o0, o1, o2, o3;
        QTRANS(v.x, v.y, v.z, v.w, o0, o1, o2, o3)  // batches 4bq+0..3 of col c+r
        const int i = c + r;
        uint32_t phys = (uint32_t)(i << 6) + (uint32_t)((bq ^ (i & 3)) << 4);
        *(float4*)(xsb + phys) = make_float4(o0, o1, o2, o3);
    }
    __syncthreads();

    // ---- gather: quad q owns units ubase..ubase+3; lane r=cq owns batches
    //      4cq..4cq+3. Per (j,k): 1 quad-uniform ds_read_b128 + 4 fmaf. ----
    const int cq = r;
    const int ubase = w * 64 + q16 * 4;
    const uint32_t e4 = (uint32_t)cq << 4;

    float acc[4][4];
#pragma unroll
    for (int j = 0; j < 4; ++j) {
        const float bv = bias[ubase + j];
#pragma unroll
        for (int c = 0; c < 4; ++c) acc[j][c] = bv;
    }

#pragma unroll
    for (int j = 0; j < 4; ++j) {
        const uint2* pkp = pkU + (size_t)(ubase + j) * KCONN;
#pragma unroll 8
        for (int k = 0; k < KCONN; ++k) {
            uint2 pk = pkp[k];                       // 256B/unit, quad-broadcast
            float4 xv = *(const float4*)(xsb + (pk.x ^ e4));
            float wv = __uint_as_float(pk.y);
            acc[j][0] = fmaf(xv.x, wv, acc[j][0]);
            acc[j][1] = fmaf(xv.y, wv, acc[j][1]);
            acc[j][2] = fmaf(xv.z, wv, acc[j][2]);
            acc[j][3] = fmaf(xv.w, wv, acc[j][3]);
        }
    }

    // ---- store: float4 over j => 4 contiguous 256B segments per instr ----
#pragma unroll
    for (int c = 0; c < 4; ++c) {
        float4 o = make_float4(acc[0][c], acc[1][c], acc[2][c], acc[3][c]);
        *(float4*)(y + (size_t)(b0 + 4 * cq + c) * UNITS + ubase) = o;
    }
}

extern "C" void kernel_launch(void* const* d_in, const int* in_sizes, int n_in,
                              void* d_out, int out_size, void* d_ws, size_t ws_size,
                              hipStream_t stream) {
    const float* x  = (const float*)d_in[0];   // [16384,1024]
    const float* W  = (const float*)d_in[1];   // [512,1024]
    const float* bv = (const float*)d_in[2];   // [512]
    const float* D  = (const float*)d_in[3];   // [512,1024]
    const float* GN = (const float*)d_in[4];   // [1,512,1024]
    float* y = (float*)d_out;                  // [16384,512]

    uint2* pkU = (uint2*)d_ws;                 // 512*32*8B = 128KB scratch

    topk_kernel<<<UNITS, 64, 0, stream>>>(D, GN, W, pkU);
    spmm_kernel<<<BATCH / BT, 512, 0, stream>>>(x, bv, pkU, y);
}

// Round 7
// 45.956 us; speedup vs baseline: 1.1890x; 1.1890x over previous
//
#include <hip/hip_runtime.h>
#include <stdint.h>

#define UNITS  512
#define IN_DIM 1024
#define KCONN  32
#define BATCH  16384
#define BT     32      // batches per block tile (f16 row = 64B)

// ---------------- Kernel 1: top-32 per unit (DPP, no DS ops) ----------------
// pert[u,i] = D[u,i] + GN[0,u,i]; select the 32 largest. Only the index SET
// matters downstream (one-hots are summed), so selection order / exact
// tie-break is irrelevant (values are continuous; exact ties ~never happen).
// Output unit-major: pkU[u*32 + k] = { px, bits(W[u,i]) } where
//   px = i*64 + ((i&3)<<4)  -- pre-swizzled LDS address of row i's chunk 0
//   (batch octet 0). Gather lane cq reads octet cq at px ^ (cq<<4).

template <int CTRL, int RM>
__device__ __forceinline__ float dppmax(float m) {
    // lanes with no valid dpp source keep old value, harmless for max
    int t = __builtin_amdgcn_update_dpp(0xFF800000, __float_as_int(m),
                                        CTRL, RM, 0xf, false);
    return fmaxf(m, __int_as_float(t));
}

__global__ __launch_bounds__(64) void topk_kernel(const float* __restrict__ D,
                                                  const float* __restrict__ GN,
                                                  const float* __restrict__ W,
                                                  uint2* __restrict__ pkU) {
    const int u = blockIdx.x;
    const int l = threadIdx.x;

    float cand[16];
#pragma unroll
    for (int j = 0; j < 16; ++j) {
        int i = l + 64 * j;                          // coalesced
        cand[j] = D[u * IN_DIM + i] + GN[u * IN_DIM + i];
    }

    int mykeep = -1;

    for (int t = 0; t < KCONN; ++t) {
        // local argmax over 16 register slots
        float bv = cand[0];
        int bs = 0;
#pragma unroll
        for (int j = 1; j < 16; ++j) {
            bool gt = cand[j] > bv;
            bv = gt ? cand[j] : bv;
            bs = gt ? j : bs;
        }
        // wave max via DPP (VALU pipe only): row_shr 1,2,4,8 + row_bcast15/31
        float m = bv;
        m = dppmax<0x111, 0xf>(m);
        m = dppmax<0x112, 0xf>(m);
        m = dppmax<0x114, 0xf>(m);
        m = dppmax<0x118, 0xf>(m);
        m = dppmax<0x142, 0xa>(m);   // row_bcast15 -> rows 1,3
        m = dppmax<0x143, 0xc>(m);   // row_bcast31 -> rows 2,3
        float gmax = __int_as_float(__builtin_amdgcn_readlane(__float_as_int(m), 63));

        unsigned long long mask = __ballot(bv == gmax);
        int owner = __ffsll((long long)mask) - 1;
        int slot = __builtin_amdgcn_readlane(bs, owner);
        int idx = slot * 64 + owner;                 // global column index

        if (l == t) mykeep = idx;
        // removal (uniform, unrolled -> no scratch)
        bool own = (l == owner);
#pragma unroll
        for (int j = 0; j < 16; ++j)
            cand[j] = (own && j == slot) ? -__builtin_huge_valf() : cand[j];
    }

    if (l < KCONN) {
        int i = mykeep;
        float w = W[u * IN_DIM + i];
        uint32_t px = ((uint32_t)i << 6) | (((uint32_t)i & 3u) << 4);
        pkU[u * KCONN + l] = make_uint2(px, __float_as_uint(w));
    }
}

// ---------------- Kernel 2: sparse gather-GEMM ----------------
// y[b,u] = bias[u] + sum_k W[u,i] * x[b,i]
// LDS: xs_T[i][b] f16, 32 batches/row = 64B rows, 64 KB -> 2 blocks/CU.
// Chunk swizzle (16B granule): octet c (batches 8c..8c+7) of row i lives at
//   i*64 + 16*(c ^ (i&3)).
// Gather: QUAD-UNIFORM FULL ROWS -- the quad's 4 lanes read the 4 chunks of
// the SAME row (one unit,k) => 32 batches (8 MACs/lane) per ds_read_b128,
// 2x r6's MACs/instr and half its bytes; every row-read covers 16 banks once.
// Each quad owns 4 units (u = w*64 + q16*4 + j); pk is unit-major (256B/unit,
// quad-broadcast, L1-friendly). acc[4][8] fully static. MAC: v_fma_mix_f32
// (1 VALU/MAC, W exact f32, f16 x-rounding ~7.8e-3 absmax as r3/r5).

// 4x4 transpose within a quad (r2-r6 verified): input lane r holds row r's
// 4 cols {c..c+3}; output lane r holds col c+r's 4 rows.
#define QTRANS(f0, f1, f2, f3, o0, o1, o2, o3)                                   \
    {                                                                            \
        float t0 = r1 ? f1 : f0, t1 = r1 ? f2 : f1, t2 = r1 ? f3 : f2,           \
              t3 = r1 ? f0 : f3;                                                 \
        float g0 = r2m ? t2 : t0, g1 = r2m ? t3 : t1, g2 = r2m ? t0 : t2,        \
              g3 = r2m ? t1 : t3;                                                \
        float m0 = __shfl(g0, qb | (r & 3), 64);                                 \
        float m1 = __shfl(g1, qb | ((r - 1) & 3), 64);                           \
        float m2 = __shfl(g2, qb | ((r - 2) & 3), 64);                           \
        float m3 = __shfl(g3, qb | ((r - 3) & 3), 64);                           \
        float e0 = m0, e1 = m3, e2 = m2, e3 = m1;                                \
        float s0 = r1 ? e3 : e0, s1 = r1 ? e0 : e1, s2 = r1 ? e1 : e2,           \
              s3 = r1 ? e2 : e3;                                                 \
        o0 = r2m ? s2 : s0; o1 = r2m ? s3 : s1; o2 = r2m ? s0 : s2;              \
        o3 = r2m ? s1 : s3;                                                      \
    }

__device__ __forceinline__ uint32_t pkh2(float a, float b) {
    union { _Float16 h; uint16_t u; } ua, ub;
    ua.h = (_Float16)a;
    ub.h = (_Float16)b;
    return (uint32_t)ua.u | ((uint32_t)ub.u << 16);
}

__device__ __forceinline__ void mix_lo(float& acc, uint32_t xh, float w) {
    asm("v_fma_mix_f32 %0, %1, %2, %0 op_sel_hi:[1,0,0]"
        : "+v"(acc) : "v"(xh), "v"(w));
}
__device__ __forceinline__ void mix_hi(float& acc, uint32_t xh, float w) {
    asm("v_fma_mix_f32 %0, %1, %2, %0 op_sel:[1,0,0] op_sel_hi:[1,0,0]"
        : "+v"(acc) : "v"(xh), "v"(w));
}

__global__ __launch_bounds__(512, 4) void spmm_kernel(const float* __restrict__ x,
                                                      const float* __restrict__ bias,
                                                      const uint2* __restrict__ pkU,
                                                      float* __restrict__ y) {
    __shared__ char xsb[65536];                     // 1024 rows x 64B

    const int tid = threadIdx.x;
    const int w = tid >> 6;                         // wave 0..7
    const int l = tid & 63;
    const int r = l & 3;                            // quad lane
    const int q16 = l >> 2;                         // quad id 0..15
    const int b0 = blockIdx.x * BT;

    // ---- stage: x[b0..b0+31][:] f32 -> f16 xs_T[i][b], transposed ----
    // wave w: batch octet a = w&3 (batches 8a..8a+7), col half Q = w>>2.
    const int a = w & 3, Q = w >> 2;
    const float* xrA = x + (size_t)(b0 + 8 * a + r) * IN_DIM;
    const float* xrB = xrA + 4 * IN_DIM;
    const int r1 = r & 1, r2m = r & 2;
    const int qb = l & ~3;
#pragma unroll
    for (int j = 0; j < 8; ++j) {
        const int c = Q * 512 + q16 * 4 + j * 64;
        float4 vA = *(const float4*)(xrA + c);
        float4 vB = *(const float4*)(xrB + c);
        float o0, o1, o2, o3, p0, p1, p2, p3;
        QTRANS(vA.x, vA.y, vA.z, vA.w, o0, o1, o2, o3)   // batches 8a+0..3 of col c+r
        QTRANS(vB.x, vB.y, vB.z, vB.w, p0, p1, p2, p3)   // batches 8a+4..7 of col c+r
        const int i = c + r;
        uint4 pkd = make_uint4(pkh2(o0, o1), pkh2(o2, o3),
                               pkh2(p0, p1), pkh2(p2, p3));
        uint32_t phys = (uint32_t)(i << 6) + (uint32_t)((a ^ (i & 3)) << 4);
        *(uint4*)(xsb + phys) = pkd;
    }
    __syncthreads();

    // ---- gather: quad q16 owns units ubase..ubase+3; lane r=cq owns batch
    //      octet cq. Per (j,k): 1 quad-uniform-row ds_read_b128 (8 batches)
    //      + 8 v_fma_mix_f32. ----
    const int cq = r;
    const int ubase = w * 64 + q16 * 4;
    const uint32_t e4 = (uint32_t)cq << 4;

    float acc[4][8];
#pragma unroll
    for (int j = 0; j < 4; ++j) {
        const float bv = bias[ubase + j];
#pragma unroll
        for (int t = 0; t < 8; ++t) acc[j][t] = bv;
    }

#pragma unroll
    for (int j = 0; j < 4; ++j) {
        const uint2* pkp = pkU + (size_t)(ubase + j) * KCONN;
#pragma unroll 8
        for (int k = 0; k < KCONN; ++k) {
            uint2 pk = pkp[k];                       // 256B/unit, quad-broadcast
            uint4 xv = *(const uint4*)(xsb + (pk.x ^ e4));   // row, octet cq
            float wv = __uint_as_float(pk.y);
            mix_lo(acc[j][0], xv.x, wv); mix_hi(acc[j][1], xv.x, wv);
            mix_lo(acc[j][2], xv.y, wv); mix_hi(acc[j][3], xv.y, wv);
            mix_lo(acc[j][4], xv.z, wv); mix_hi(acc[j][5], xv.z, wv);
            mix_lo(acc[j][6], xv.w, wv); mix_hi(acc[j][7], xv.w, wv);
        }
    }

    // ---- store: float4 over j => 4x256B contiguous segments per instr ----
#pragma unroll
    for (int t = 0; t < 8; ++t) {
        float4 o = make_float4(acc[0][t], acc[1][t], acc[2][t], acc[3][t]);
        *(float4*)(y + (size_t)(b0 + 8 * cq + t) * UNITS + ubase) = o;
    }
}

extern "C" void kernel_launch(void* const* d_in, const int* in_sizes, int n_in,
                              void* d_out, int out_size, void* d_ws, size_t ws_size,
                              hipStream_t stream) {
    const float* x  = (const float*)d_in[0];   // [16384,1024]
    const float* W  = (const float*)d_in[1];   // [512,1024]
    const float* bv = (const float*)d_in[2];   // [512]
    const float* D  = (const float*)d_in[3];   // [512,1024]
    const float* GN = (const float*)d_in[4];   // [1,512,1024]
    float* y = (float*)d_out;                  // [16384,512]

    uint2* pkU = (uint2*)d_ws;                 // 512*32*8B = 128KB scratch

    topk_kernel<<<UNITS, 64, 0, stream>>>(D, GN, W, pkU);
    spmm_kernel<<<BATCH / BT, 512, 0, stream>>>(x, bv, pkU, y);
}

// Round 8
// 45.076 us; speedup vs baseline: 1.2122x; 1.0195x over previous
//
#include <hip/hip_runtime.h>
#include <stdint.h>

#define UNITS  512
#define IN_DIM 1024
#define KCONN  32
#define BATCH  16384
#define BT     32      // batches per block tile (f16 row = 64B)

// ---------------- Kernel 1: top-32 per unit (DPP, no DS ops) ----------------
// pert[u,i] = D[u,i] + GN[0,u,i]; select the 32 largest. Only the index SET
// matters downstream (one-hots are summed), so selection order / exact
// tie-break is irrelevant (values are continuous; exact ties ~never happen).
// Output unit-major: pkU[u*32 + k] = { px, bits(W[u,i]) } where
//   px = i*64 + ((i&3)<<4)  -- pre-swizzled LDS address of row i's octet 0.
//   Gather lane cq reads octet cq at px ^ (cq<<4).

template <int CTRL, int RM>
__device__ __forceinline__ float dppmax(float m) {
    // lanes with no valid dpp source keep old value, harmless for max
    int t = __builtin_amdgcn_update_dpp(0xFF800000, __float_as_int(m),
                                        CTRL, RM, 0xf, false);
    return fmaxf(m, __int_as_float(t));
}

__global__ __launch_bounds__(64) void topk_kernel(const float* __restrict__ D,
                                                  const float* __restrict__ GN,
                                                  const float* __restrict__ W,
                                                  uint2* __restrict__ pkU) {
    const int u = blockIdx.x;
    const int l = threadIdx.x;

    float cand[16];
#pragma unroll
    for (int j = 0; j < 16; ++j) {
        int i = l + 64 * j;                          // coalesced
        cand[j] = D[u * IN_DIM + i] + GN[u * IN_DIM + i];
    }

    int mykeep = -1;

    for (int t = 0; t < KCONN; ++t) {
        // local argmax over 16 register slots
        float bv = cand[0];
        int bs = 0;
#pragma unroll
        for (int j = 1; j < 16; ++j) {
            bool gt = cand[j] > bv;
            bv = gt ? cand[j] : bv;
            bs = gt ? j : bs;
        }
        // wave max via DPP (VALU pipe only): row_shr 1,2,4,8 + row_bcast15/31
        float m = bv;
        m = dppmax<0x111, 0xf>(m);
        m = dppmax<0x112, 0xf>(m);
        m = dppmax<0x114, 0xf>(m);
        m = dppmax<0x118, 0xf>(m);
        m = dppmax<0x142, 0xa>(m);   // row_bcast15 -> rows 1,3
        m = dppmax<0x143, 0xc>(m);   // row_bcast31 -> rows 2,3
        float gmax = __int_as_float(__builtin_amdgcn_readlane(__float_as_int(m), 63));

        unsigned long long mask = __ballot(bv == gmax);
        int owner = __ffsll((long long)mask) - 1;
        int slot = __builtin_amdgcn_readlane(bs, owner);
        int idx = slot * 64 + owner;                 // global column index

        if (l == t) mykeep = idx;
        // removal (uniform, unrolled -> no scratch)
        bool own = (l == owner);
#pragma unroll
        for (int j = 0; j < 16; ++j)
            cand[j] = (own && j == slot) ? -__builtin_huge_valf() : cand[j];
    }

    if (l < KCONN) {
        int i = mykeep;
        float w = W[u * IN_DIM + i];
        uint32_t px = ((uint32_t)i << 6) | (((uint32_t)i & 3u) << 4);
        pkU[u * KCONN + l] = make_uint2(px, __float_as_uint(w));
    }
}

// ---------------- Kernel 2: sparse gather-GEMM ----------------
// y[b,u] = bias[u] + sum_k W[u,i] * x[b,i]
// LDS: xs_T[i][b] f16, 32 batches/row = 64B rows, 64 KB -> 2 blocks/CU.
// Octet swizzle (16B): octet c of row i lives at i*64 + 16*(c ^ (i&3)).
// Gather: quad-uniform full rows (r7); NEW: pk entries are loaded as uint4
// K-PAIRS with an explicit one-iteration-ahead software pipeline, so the
// global(L2)->ds_read->fma dependency chain is broken: pk latency hides under
// the previous pair's 8 ds_read + 64 fma (~270 cyc). Only the ~120cyc LDS
// latency stays in-chain (7 waves hide it; 16 resident).

// 4x4 transpose within a quad (r2-r7 verified): input lane r holds row r's
// 4 cols {c..c+3}; output lane r holds col c+r's 4 rows.
#define QTRANS(f0, f1, f2, f3, o0, o1, o2, o3)                                   \
    {                                                                            \
        float t0 = r1 ? f1 : f0, t1 = r1 ? f2 : f1, t2 = r1 ? f3 : f2,           \
              t3 = r1 ? f0 : f3;                                                 \
        float g0 = r2m ? t2 : t0, g1 = r2m ? t3 : t1, g2 = r2m ? t0 : t2,        \
              g3 = r2m ? t1 : t3;                                                \
        float m0 = __shfl(g0, qb | (r & 3), 64);                                 \
        float m1 = __shfl(g1, qb | ((r - 1) & 3), 64);                           \
        float m2 = __shfl(g2, qb | ((r - 2) & 3), 64);                           \
        float m3 = __shfl(g3, qb | ((r - 3) & 3), 64);                           \
        float e0 = m0, e1 = m3, e2 = m2, e3 = m1;                                \
        float s0 = r1 ? e3 : e0, s1 = r1 ? e0 : e1, s2 = r1 ? e1 : e2,           \
              s3 = r1 ? e2 : e3;                                                 \
        o0 = r2m ? s2 : s0; o1 = r2m ? s3 : s1; o2 = r2m ? s0 : s2;              \
        o3 = r2m ? s1 : s3;                                                      \
    }

__device__ __forceinline__ uint32_t pkh2(float a, float b) {
    union { _Float16 h; uint16_t u; } ua, ub;
    ua.h = (_Float16)a;
    ub.h = (_Float16)b;
    return (uint32_t)ua.u | ((uint32_t)ub.u << 16);
}

__device__ __forceinline__ void mix_lo(float& acc, uint32_t xh, float w) {
    asm("v_fma_mix_f32 %0, %1, %2, %0 op_sel_hi:[1,0,0]"
        : "+v"(acc) : "v"(xh), "v"(w));
}
__device__ __forceinline__ void mix_hi(float& acc, uint32_t xh, float w) {
    asm("v_fma_mix_f32 %0, %1, %2, %0 op_sel:[1,0,0] op_sel_hi:[1,0,0]"
        : "+v"(acc) : "v"(xh), "v"(w));
}

// consume one k-pair for unit-slot aj: cur = {px_even, W_even, px_odd, W_odd}
#define PKMAC(cur, aj)                                                           \
    {                                                                            \
        uint4 xe = *(const uint4*)(xsb + (cur.x ^ e4));                          \
        uint4 xo = *(const uint4*)(xsb + (cur.z ^ e4));                          \
        float we = __uint_as_float(cur.y), wo = __uint_as_float(cur.w);          \
        mix_lo(acc[aj][0], xe.x, we); mix_hi(acc[aj][1], xe.x, we);              \
        mix_lo(acc[aj][2], xe.y, we); mix_hi(acc[aj][3], xe.y, we);              \
        mix_lo(acc[aj][4], xe.z, we); mix_hi(acc[aj][5], xe.z, we);              \
        mix_lo(acc[aj][6], xe.w, we); mix_hi(acc[aj][7], xe.w, we);              \
        mix_lo(acc[aj][0], xo.x, wo); mix_hi(acc[aj][1], xo.x, wo);              \
        mix_lo(acc[aj][2], xo.y, wo); mix_hi(acc[aj][3], xo.y, wo);              \
        mix_lo(acc[aj][4], xo.z, wo); mix_hi(acc[aj][5], xo.z, wo);              \
        mix_lo(acc[aj][6], xo.w, wo); mix_hi(acc[aj][7], xo.w, wo);              \
    }

__global__ __launch_bounds__(512, 4) void spmm_kernel(const float* __restrict__ x,
                                                      const float* __restrict__ bias,
                                                      const uint2* __restrict__ pkU,
                                                      float* __restrict__ y) {
    __shared__ char xsb[65536];                     // 1024 rows x 64B

    const int tid = threadIdx.x;
    const int w = tid >> 6;                         // wave 0..7
    const int l = tid & 63;
    const int r = l & 3;                            // quad lane
    const int q16 = l >> 2;                         // quad id 0..15
    const int b0 = blockIdx.x * BT;

    // ---- stage: x[b0..b0+31][:] f32 -> f16 xs_T[i][b], transposed ----
    // wave w: batch octet a = w&3 (batches 8a..8a+7), col half Q = w>>2.
    const int a = w & 3, Q = w >> 2;
    const float* xrA = x + (size_t)(b0 + 8 * a + r) * IN_DIM;
    const float* xrB = xrA + 4 * IN_DIM;
    const int r1 = r & 1, r2m = r & 2;
    const int qb = l & ~3;
#pragma unroll
    for (int j = 0; j < 8; ++j) {
        const int c = Q * 512 + q16 * 4 + j * 64;
        float4 vA = *(const float4*)(xrA + c);
        float4 vB = *(const float4*)(xrB + c);
        float o0, o1, o2, o3, p0, p1, p2, p3;
        QTRANS(vA.x, vA.y, vA.z, vA.w, o0, o1, o2, o3)   // batches 8a+0..3 of col c+r
        QTRANS(vB.x, vB.y, vB.z, vB.w, p0, p1, p2, p3)   // batches 8a+4..7 of col c+r
        const int i = c + r;
        uint4 pkd = make_uint4(pkh2(o0, o1), pkh2(o2, o3),
                               pkh2(p0, p1), pkh2(p2, p3));
        uint32_t phys = (uint32_t)(i << 6) + (uint32_t)((a ^ (i & 3)) << 4);
        *(uint4*)(xsb + phys) = pkd;
    }
    __syncthreads();

    // ---- gather: quad q16 owns units ubase..ubase+3; lane r=cq owns batch
    //      octet cq. k-pairs, one-ahead pk prefetch. ----
    const int cq = r;
    const int ubase = w * 64 + q16 * 4;
    const uint32_t e4 = (uint32_t)cq << 4;

    float acc[4][8];
#pragma unroll
    for (int j = 0; j < 4; ++j) {
        const float bv = bias[ubase + j];
#pragma unroll
        for (int t = 0; t < 8; ++t) acc[j][t] = bv;
    }

    const uint4* pp0 = (const uint4*)(pkU + (size_t)(ubase + 0) * KCONN);
    const uint4* pp1 = (const uint4*)(pkU + (size_t)(ubase + 1) * KCONN);
    const uint4* pp2 = (const uint4*)(pkU + (size_t)(ubase + 2) * KCONN);
    const uint4* pp3 = (const uint4*)(pkU + (size_t)(ubase + 3) * KCONN);

    uint4 c0 = pp0[0], c1 = pp1[0], c2 = pp2[0], c3 = pp3[0];

#pragma unroll 4
    for (int kp = 0; kp < KCONN / 2; ++kp) {
        const int kn = (kp + 1 < KCONN / 2) ? kp + 1 : kp;   // tail reload, harmless
        uint4 n0 = pp0[kn];                        // issue next pair's loads FIRST
        uint4 n1 = pp1[kn];
        uint4 n2 = pp2[kn];
        uint4 n3 = pp3[kn];
        PKMAC(c0, 0)
        PKMAC(c1, 1)
        PKMAC(c2, 2)
        PKMAC(c3, 3)
        c0 = n0; c1 = n1; c2 = n2; c3 = n3;
    }

    // ---- store: float4 over j => 4x256B contiguous segments per instr ----
#pragma unroll
    for (int t = 0; t < 8; ++t) {
        float4 o = make_float4(acc[0][t], acc[1][t], acc[2][t], acc[3][t]);
        *(float4*)(y + (size_t)(b0 + 8 * cq + t) * UNITS + ubase) = o;
    }
}

extern "C" void kernel_launch(void* const* d_in, const int* in_sizes, int n_in,
                              void* d_out, int out_size, void* d_ws, size_t ws_size,
                              hipStream_t stream) {
    const float* x  = (const float*)d_in[0];   // [16384,1024]
    const float* W  = (const float*)d_in[1];   // [512,1024]
    const float* bv = (const float*)d_in[2];   // [512]
    const float* D  = (const float*)d_in[3];   // [512,1024]
    const float* GN = (const float*)d_in[4];   // [1,512,1024]
    float* y = (float*)d_out;                  // [16384,512]

    uint2* pkU = (uint2*)d_ws;                 // 512*32*8B = 128KB scratch

    topk_kernel<<<UNITS, 64, 0, stream>>>(D, GN, W, pkU);
    spmm_kernel<<<BATCH / BT, 512, 0, stream>>>(x, bv, pkU, y);
}